// Round 4
// baseline (1348.656 us; speedup 1.0000x reference)
//
#include <hip/hip_runtime.h>

typedef __attribute__((ext_vector_type(8))) short short8;
typedef __attribute__((ext_vector_type(8))) unsigned short ushort8;
typedef __attribute__((ext_vector_type(4))) float f32x4;

#define K_DIM 70400   // 275 groups * 256 ci ; group g = v*5+kw
#define KHALF 1100    // K-tiles of 32 per k-split half (2200 total)
#define XROWS 118
#define XCOLS 68
#define BUF 16384     // elems per LDS buffer: A 256x32 (8192) + B 256x32 (8192)
#define BOFFB 8192

#define XPACK_ELEMS (8 * XROWS * XCOLS * 256)
#define XPACK_BYTES (XPACK_ELEMS * 2)
#define APACK_ELEMS (256 * K_DIM)
#define APACK_BYTES (APACK_ELEMS * 2)

static __device__ __forceinline__ unsigned short f2bf(float f) {
    unsigned u = __builtin_bit_cast(unsigned, f);
    u += 0x7fffu + ((u >> 16) & 1u);
    return (unsigned short)(u >> 16);
}

static __device__ __forceinline__ void mfma16(f32x4& acc, short8 a, short8 b) {
    asm("v_mfma_f32_16x16x32_bf16 %0, %1, %2, %0" : "+v"(acc) : "v"(a), "v"(b));
}

#define GLOAD_LDS(gp, lp) __builtin_amdgcn_global_load_lds( \
    (const __attribute__((address_space(1))) void*)(gp),    \
    (__attribute__((address_space(3))) void*)(lp), 16, 0, 0)

#define BAR() __builtin_amdgcn_s_barrier()
#define LGKM0() do { asm volatile("s_waitcnt lgkmcnt(0)" ::: "memory"); \
                     __builtin_amdgcn_sched_barrier(0); } while (0)

// ---------------- pack kernels ----------------

__global__ __launch_bounds__(256) void zero_ws_kernel(ushort8* __restrict__ p, int n) {
    int i = blockIdx.x * 256 + threadIdx.x;
    if (i < n) { ushort8 z = {}; p[i] = z; }
}

__global__ __launch_bounds__(256) void zero_out_kernel(f32x4* __restrict__ p) {
    int i = blockIdx.x * 256 + threadIdx.x;   // 2,097,152 f32x4
    f32x4 z = {};
    p[i] = z;
}

__global__ __launch_bounds__(256) void pack_x_kernel(const float* __restrict__ x,
                                                     unsigned short* __restrict__ xp) {
    int g = blockIdx.x * 256 + threadIdx.x;
    int xc = g & 63;
    int rest = g >> 6;
    int chunk = rest & 31;
    int br = rest >> 5;
    int xr = br & 63;
    int b  = br >> 6;
    const float* src = x + (long)(b * 256 + chunk * 8) * 4096 + xr * 64 + xc;
    ushort8 o;
#pragma unroll
    for (int e = 0; e < 8; ++e) o[e] = f2bf(src[(long)e * 4096]);
    long off = ((long)((b * XROWS + xr + 25) * XCOLS + (xc + 2))) * 256 + chunk * 8;
    *(ushort8*)(xp + off) = o;
}

__global__ __launch_bounds__(256) void pack_w_kernel(const float* __restrict__ W,
                                                     unsigned short* __restrict__ Apk) {
    int c = blockIdx.x, t = threadIdx.x;
    __shared__ float lw[6400];
    for (int idx = 0; idx < 11; ++idx) {
        const float* src = W + (long)(c * 11 + idx) * 6400;
        for (int e = t; e < 6400; e += 256) lw[e] = src[e];
        __syncthreads();
#pragma unroll 5
        for (int khw = 0; khw < 25; ++khw)
            Apk[(long)c * K_DIM + (idx * 25 + khw) * 256 + t] = f2bf(lw[t * 25 + khw]);
        __syncthreads();
    }
}

// ---------------- GEMM: 256x32768x70400, BM=256 BN=256 BK=32, ksplit=2 ----------------
// 256 blocks x 512 thr, 8 waves 2Mx4N, per-wave 128x64, quad-buffered LDS.
__global__ __launch_bounds__(512) void gemm_kernel(const unsigned short* __restrict__ Apk,
                                                   const unsigned short* __restrict__ Xpk,
                                                   float* __restrict__ out) {
    __shared__ unsigned short lds[4 * BUF];   // 128 KiB
    const int t = threadIdx.x;
    int bid = blockIdx.x;
    int swz = (bid & 7) * 32 + (bid >> 3);    // bijective XCD swizzle (256 % 8 == 0)
    const int nt = swz >> 1;                  // 0..127
    const int ks = swz & 1;                   // k-split half; pair shares B panel/XCD
    const int n0 = nt * 256;
    const int k0 = ks * KHALF;

    const int lane = t & 63;
    const int w = t >> 6;
    const int wm = w >> 2;          // 0..1
    const int wn = w & 3;           // 0..3
    const int lrow = lane & 15;
    const int lsg = lane >> 4;

    // fragment LDS offsets (elems); T2 swizzle: 16B slot ^= row&3 (both sides)
    int offA[8], offB[4];
#pragma unroll
    for (int m = 0; m < 8; ++m) {
        int ra = wm * 128 + m * 16 + lrow;
        offA[m] = ra * 32 + ((lsg ^ (ra & 3)) << 3);
    }
#pragma unroll
    for (int nf = 0; nf < 4; ++nf) {
        int rb = wn * 64 + nf * 16 + lrow;
        offB[nf] = BOFFB + rb * 32 + ((lsg ^ (rb & 3)) << 3);
    }

    // staging: linear LDS dest chunk ch=(row,s); global source slot s^(row&3)
    const unsigned short* aS[2];
    const unsigned short* bS[2];
    int aD[2], bD[2];
#pragma unroll
    for (int p = 0; p < 2; ++p) {
        int ch = p * 512 + t;
        int row = ch >> 2;
        int s = (ch & 3) ^ (row & 3);
        aS[p] = Apk + (long)row * K_DIM + s * 8;
        aD[p] = ch * 8;
        int n = n0 + row;
        int b = n >> 12, i = (n >> 6) & 63, j = n & 63;
        bS[p] = Xpk + ((long)((b * XROWS + i) * XCOLS + j)) * 256 + s * 8;
        bD[p] = BOFFB + ch * 8;
    }

    // prologue: stage tiles k0..k0+2 (4 loads each), wait for tile 0 (vmcnt(8))
#pragma unroll
    for (int pre = 0; pre < 3; ++pre) {
        int kt = k0 + pre;
        int qB = pre * BUF;
        int dA = kt << 5;
        int g = kt >> 3, v = g / 5, kw = g - v * 5;
        int dB = (v * XCOLS + kw) * 256 + ((kt & 7) << 5);
        GLOAD_LDS(aS[0] + dA, lds + qB + aD[0]);
        GLOAD_LDS(aS[1] + dA, lds + qB + aD[1]);
        GLOAD_LDS(bS[0] + dB, lds + qB + bD[0]);
        GLOAD_LDS(bS[1] + dB, lds + qB + bD[1]);
    }
    asm volatile("s_waitcnt vmcnt(8)" ::: "memory");
    BAR();

    f32x4 acc[8][4] = {};

    for (int ktl = 0; ktl < KHALF; ++ktl) {
        const int qcB = (ktl & 3) * BUF;
        const int qsB = ((ktl + 3) & 3) * BUF;
        const bool st = (ktl + 3) < KHALF;
        const int kt3 = k0 + ktl + 3;
        const int dA3 = kt3 << 5;
        int g3 = kt3 >> 3, v3 = g3 / 5, kw3 = g3 - v3 * 5;
        const int dB3 = (v3 * XCOLS + kw3) * 256 + ((kt3 & 7) << 5);

        short8 af[8], b0, b1, b2, b3;
        // ---- phase 0: all ds_reads + A-stage, MFMA on n0/n1
#pragma unroll
        for (int m = 0; m < 8; ++m) af[m] = *(const short8*)(lds + qcB + offA[m]);
        b0 = *(const short8*)(lds + qcB + offB[0]);
        b1 = *(const short8*)(lds + qcB + offB[1]);
        b2 = *(const short8*)(lds + qcB + offB[2]);
        b3 = *(const short8*)(lds + qcB + offB[3]);
        if (st) { GLOAD_LDS(aS[0] + dA3, lds + qsB + aD[0]);
                  GLOAD_LDS(aS[1] + dA3, lds + qsB + aD[1]); }
        BAR(); LGKM0();
        __builtin_amdgcn_s_setprio(1);
#pragma unroll
        for (int m = 0; m < 8; ++m) { mfma16(acc[m][0], af[m], b0); mfma16(acc[m][1], af[m], b1); }
        __builtin_amdgcn_s_setprio(0);
        BAR();
        // ---- phase 1: B-stage, MFMA on n2/n3, counted boundary vmcnt
        if (st) { GLOAD_LDS(bS[0] + dB3, lds + qsB + bD[0]);
                  GLOAD_LDS(bS[1] + dB3, lds + qsB + bD[1]); }
        BAR(); LGKM0();
        __builtin_amdgcn_s_setprio(1);
#pragma unroll
        for (int m = 0; m < 8; ++m) { mfma16(acc[m][2], af[m], b2); mfma16(acc[m][3], af[m], b3); }
        __builtin_amdgcn_s_setprio(0);
        if (st) asm volatile("s_waitcnt vmcnt(8)" ::: "memory");
        else    asm volatile("s_waitcnt vmcnt(0)" ::: "memory");
        BAR();
    }

    // epilogue: C/D row=(lane>>4)*4+reg, col=lane&15 [m89]; k-split -> f32 HW atomics
    const int b = n0 >> 12;
    float* ob = out + (long)b * 1048576 + (n0 & 4095) + wn * 64 + (lane & 15);
#pragma unroll
    for (int m = 0; m < 8; ++m)
#pragma unroll
        for (int qi = 0; qi < 4; ++qi) {
            int row = wm * 128 + m * 16 + (lane >> 4) * 4 + qi;
            float* orow = ob + (long)row * 4096;
#pragma unroll
            for (int nf = 0; nf < 4; ++nf)
                unsafeAtomicAdd(orow + nf * 16, acc[m][nf][qi]);
        }
}

// ---------------- BatchNorm ----------------

__global__ __launch_bounds__(256) void bn_stats_kernel(const float* __restrict__ out,
                                                       const float* __restrict__ gamma,
                                                       const float* __restrict__ beta,
                                                       float* __restrict__ bnp) {
    int c = blockIdx.x, t = threadIdx.x;
    float s = 0.f, q = 0.f;
    for (int b = 0; b < 8; ++b) {
        const float* p = out + (long)b * 1048576 + (long)c * 4096;
        for (int e = t; e < 4096; e += 256) { float v = p[e]; s += v; q += v * v; }
    }
#pragma unroll
    for (int off = 32; off > 0; off >>= 1) { s += __shfl_down(s, off); q += __shfl_down(q, off); }
    __shared__ float ls[4], lq[4];
    int w = t >> 6;
    if ((t & 63) == 0) { ls[w] = s; lq[w] = q; }
    __syncthreads();
    if (t == 0) {
        s = ls[0] + ls[1] + ls[2] + ls[3];
        q = lq[0] + lq[1] + lq[2] + lq[3];
        float mean = s * (1.f / 32768.f);
        float var = q * (1.f / 32768.f) - mean * mean;
        float sc = gamma[c] * rsqrtf(var + 1e-5f);
        bnp[c] = sc;
        bnp[256 + c] = beta[c] - mean * sc;
    }
}

__global__ __launch_bounds__(256) void bn_apply_kernel(float* __restrict__ out,
                                                       const float* __restrict__ bnp) {
    int i = blockIdx.x * 256 + threadIdx.x;
    f32x4* p = (f32x4*)out;
    f32x4 v = p[i];
    int c = (i >> 10) & 255;
    float sc = bnp[c], sh = bnp[256 + c];
    v = v * sc + sh;
    p[i] = v;
}

// ---------------- launch ----------------

extern "C" void kernel_launch(void* const* d_in, const int* in_sizes, int n_in,
                              void* d_out, int out_size, void* d_ws, size_t ws_size,
                              hipStream_t stream) {
    const float* x     = (const float*)d_in[0];
    const float* wgt   = (const float*)d_in[1];
    const float* gamma = (const float*)d_in[2];
    const float* beta  = (const float*)d_in[3];
    float* out = (float*)d_out;

    unsigned short* xp  = (unsigned short*)d_ws;
    unsigned short* Apk = (unsigned short*)((char*)d_ws + XPACK_BYTES);
    float* bnp          = (float*)((char*)d_ws + XPACK_BYTES + APACK_BYTES);

    zero_ws_kernel<<<8024, 256, 0, stream>>>((ushort8*)xp, XPACK_ELEMS / 8);
    pack_x_kernel<<<4096, 256, 0, stream>>>(x, xp);
    pack_w_kernel<<<256, 256, 0, stream>>>(wgt, Apk);
    zero_out_kernel<<<8192, 256, 0, stream>>>((f32x4*)out);
    gemm_kernel<<<256, 512, 0, stream>>>(Apk, xp, out);
    bn_stats_kernel<<<256, 256, 0, stream>>>(out, gamma, beta, bnp);
    bn_apply_kernel<<<8192, 256, 0, stream>>>(out, bnp);
}

// Round 5
// 1090.697 us; speedup vs baseline: 1.2365x; 1.2365x over previous
//
#include <hip/hip_runtime.h>

typedef __attribute__((ext_vector_type(8))) short short8;
typedef __attribute__((ext_vector_type(8))) unsigned short ushort8;
typedef __attribute__((ext_vector_type(4))) float f32x4;

#define K_DIM 70400   // 275 groups * 256 ci ; group g = v*5+kw
#define KHALF 550     // K-tiles of 64 per k-split half (1100 total)
#define XROWS 118
#define XCOLS 68
#define BUF32 32768   // elems per LDS buffer: A 256x64 (16384) + B 256x64 (16384)
#define BOFFB 16384

#define XPACK_ELEMS (8 * XROWS * XCOLS * 256)
#define XPACK_BYTES (XPACK_ELEMS * 2)
#define APACK_ELEMS (256 * K_DIM)
#define APACK_BYTES (APACK_ELEMS * 2)

static __device__ __forceinline__ unsigned short f2bf(float f) {
    unsigned u = __builtin_bit_cast(unsigned, f);
    u += 0x7fffu + ((u >> 16) & 1u);
    return (unsigned short)(u >> 16);
}

static __device__ __forceinline__ void mfma16(f32x4& acc, short8 a, short8 b) {
    asm("v_mfma_f32_16x16x32_bf16 %0, %1, %2, %0" : "+v"(acc) : "v"(a), "v"(b));
}

#define GLOAD_LDS(gp, lp) __builtin_amdgcn_global_load_lds( \
    (const __attribute__((address_space(1))) void*)(gp),    \
    (__attribute__((address_space(3))) void*)(lp), 16, 0, 0)

#define BAR() __builtin_amdgcn_s_barrier()
#define LGKM0() do { asm volatile("s_waitcnt lgkmcnt(0)" ::: "memory"); \
                     __builtin_amdgcn_sched_barrier(0); } while (0)

// ---------------- pack kernels ----------------

__global__ __launch_bounds__(256) void zero_ws_kernel(ushort8* __restrict__ p, int n) {
    int i = blockIdx.x * 256 + threadIdx.x;
    if (i < n) { ushort8 z = {}; p[i] = z; }
}

__global__ __launch_bounds__(256) void zero_out_kernel(f32x4* __restrict__ p) {
    int i = blockIdx.x * 256 + threadIdx.x;   // 2,097,152 f32x4
    f32x4 z = {};
    p[i] = z;
}

__global__ __launch_bounds__(256) void pack_x_kernel(const float* __restrict__ x,
                                                     unsigned short* __restrict__ xp) {
    int g = blockIdx.x * 256 + threadIdx.x;
    int xc = g & 63;
    int rest = g >> 6;
    int chunk = rest & 31;
    int br = rest >> 5;
    int xr = br & 63;
    int b  = br >> 6;
    const float* src = x + (long)(b * 256 + chunk * 8) * 4096 + xr * 64 + xc;
    ushort8 o;
#pragma unroll
    for (int e = 0; e < 8; ++e) o[e] = f2bf(src[(long)e * 4096]);
    long off = ((long)((b * XROWS + xr + 25) * XCOLS + (xc + 2))) * 256 + chunk * 8;
    *(ushort8*)(xp + off) = o;
}

__global__ __launch_bounds__(256) void pack_w_kernel(const float* __restrict__ W,
                                                     unsigned short* __restrict__ Apk) {
    int c = blockIdx.x, t = threadIdx.x;
    __shared__ float lw[6400];
    for (int idx = 0; idx < 11; ++idx) {
        const float* src = W + (long)(c * 11 + idx) * 6400;
        for (int e = t; e < 6400; e += 256) lw[e] = src[e];
        __syncthreads();
#pragma unroll 5
        for (int khw = 0; khw < 25; ++khw)
            Apk[(long)c * K_DIM + (idx * 25 + khw) * 256 + t] = f2bf(lw[t * 25 + khw]);
        __syncthreads();
    }
}

// ---------------- GEMM: 256x32768x70400, BM=256 BN=256 BK=64, ksplit=2 ----------------
// 256 blocks x 512 thr, 8 waves 2Mx4N, per-wave 128x64, double-buffered LDS (2x64KB),
// 4-phase interleave per K-tile (m201-style), setprio, boundary drain w/ 2-phase lead.
__global__ __launch_bounds__(512) void gemm_kernel(const unsigned short* __restrict__ Apk,
                                                   const unsigned short* __restrict__ Xpk,
                                                   float* __restrict__ out) {
    __shared__ unsigned short lds[2 * BUF32];   // 128 KiB
    const int t = threadIdx.x;
    int bid = blockIdx.x;
    int swz = (bid & 7) * 32 + (bid >> 3);    // bijective XCD swizzle (256 % 8 == 0)
    const int nt = swz >> 1;                  // 0..127
    const int ks = swz & 1;                   // k-split half
    const int n0 = nt * 256;
    const int k0 = ks * KHALF;

    const int lane = t & 63;
    const int w = t >> 6;
    const int wm = w >> 2;          // 0..1 -> A rows wm*128..+128
    const int wn = w & 3;           // 0..3 -> B rows wn*64..+64
    const int lrow = lane & 15;
    const int lsg = lane >> 4;

    // fragment LDS offsets; T2 swizzle (proven 0-conflict at 128B rows): slot ^= row&7
    int offA[8][2], offB[4][2];
#pragma unroll
    for (int mf = 0; mf < 8; ++mf)
#pragma unroll
        for (int kk = 0; kk < 2; ++kk) {
            int sd = kk * 4 + lsg;
            int ra = wm * 128 + mf * 16 + lrow;
            offA[mf][kk] = ra * 64 + ((sd ^ (ra & 7)) << 3);
        }
#pragma unroll
    for (int nf = 0; nf < 4; ++nf)
#pragma unroll
        for (int kk = 0; kk < 2; ++kk) {
            int sd = kk * 4 + lsg;
            int rb = wn * 64 + nf * 16 + lrow;
            offB[nf][kk] = BOFFB + rb * 64 + ((sd ^ (rb & 7)) << 3);
        }

    // staging: 4 chunks of 64 rows each for A and B; linear LDS dest, swizzled source
    const unsigned short* aS[4];
    const unsigned short* bS[4];
    int aD[4], bD[4];
    {
        int s = (t & 7) ^ ((t >> 3) & 7);     // row&7 == (t>>3)&7 for all chunks
#pragma unroll
        for (int p = 0; p < 4; ++p) {
            int ch = p * 512 + t;
            int row = p * 64 + (t >> 3);
            aS[p] = Apk + (long)row * K_DIM + s * 8;
            aD[p] = ch * 8;
            int n = n0 + row;
            int b = n >> 12, i = (n >> 6) & 63, j = n & 63;
            bS[p] = Xpk + ((long)((b * XROWS + i) * XCOLS + j)) * 256 + s * 8;
            bD[p] = BOFFB + ch * 8;
        }
    }

    // prologue: stage tile k0 into buf0, full drain
    {
        int kt = k0;
        int dA = kt << 6;
        int g = kt >> 2, v = g / 5, kw = g - v * 5;
        int dB = (v * XCOLS + kw) * 256 + ((kt & 3) << 6);
#pragma unroll
        for (int p = 0; p < 4; ++p) GLOAD_LDS(aS[p] + dA, lds + aD[p]);
#pragma unroll
        for (int p = 0; p < 4; ++p) GLOAD_LDS(bS[p] + dB, lds + bD[p]);
    }
    asm volatile("s_waitcnt vmcnt(0)" ::: "memory");
    BAR();

    f32x4 acc[8][4] = {};

    for (int ktl = 0; ktl < KHALF; ++ktl) {
        const int cur = (ktl & 1) * BUF32;
        const int nxt = ((ktl + 1) & 1) * BUF32;
        const bool st = (ktl + 1) < KHALF;
        const int kt1 = k0 + ktl + 1;
        const int dA1 = kt1 << 6;
        int g1 = kt1 >> 2, v1 = g1 / 5, kw1 = g1 - v1 * 5;
        const int dB1 = (v1 * XCOLS + kw1) * 256 + ((kt1 & 3) << 6);

        short8 af[4][2], bf[4][2];
        // ---- P0: read af(m0-3) + bf(n0,n1); stage all 4 A chunks of t+1
#pragma unroll
        for (int mf = 0; mf < 4; ++mf) { af[mf][0] = *(const short8*)(lds + cur + offA[mf][0]);
                                         af[mf][1] = *(const short8*)(lds + cur + offA[mf][1]); }
        bf[0][0] = *(const short8*)(lds + cur + offB[0][0]);
        bf[0][1] = *(const short8*)(lds + cur + offB[0][1]);
        bf[1][0] = *(const short8*)(lds + cur + offB[1][0]);
        bf[1][1] = *(const short8*)(lds + cur + offB[1][1]);
        if (st) {
#pragma unroll
            for (int p = 0; p < 4; ++p) GLOAD_LDS(aS[p] + dA1, lds + nxt + aD[p]);
        }
        BAR(); LGKM0();
        __builtin_amdgcn_s_setprio(1);
#pragma unroll
        for (int mf = 0; mf < 4; ++mf)
#pragma unroll
            for (int kk = 0; kk < 2; ++kk) { mfma16(acc[mf][0], af[mf][kk], bf[0][kk]);
                                             mfma16(acc[mf][1], af[mf][kk], bf[1][kk]); }
        __builtin_amdgcn_s_setprio(0);
        BAR();
        // ---- P1: read bf(n2,n3); stage all 4 B chunks of t+1
        bf[2][0] = *(const short8*)(lds + cur + offB[2][0]);
        bf[2][1] = *(const short8*)(lds + cur + offB[2][1]);
        bf[3][0] = *(const short8*)(lds + cur + offB[3][0]);
        bf[3][1] = *(const short8*)(lds + cur + offB[3][1]);
        if (st) {
#pragma unroll
            for (int p = 0; p < 4; ++p) GLOAD_LDS(bS[p] + dB1, lds + nxt + bD[p]);
        }
        BAR(); LGKM0();
        __builtin_amdgcn_s_setprio(1);
#pragma unroll
        for (int mf = 0; mf < 4; ++mf)
#pragma unroll
            for (int kk = 0; kk < 2; ++kk) { mfma16(acc[mf][2], af[mf][kk], bf[2][kk]);
                                             mfma16(acc[mf][3], af[mf][kk], bf[3][kk]); }
        __builtin_amdgcn_s_setprio(0);
        BAR();
        // ---- P2: read af(m4-7); MFMA m4-7 x n0,n1 (bf01 still live)
#pragma unroll
        for (int mf = 0; mf < 4; ++mf) { af[mf][0] = *(const short8*)(lds + cur + offA[mf + 4][0]);
                                         af[mf][1] = *(const short8*)(lds + cur + offA[mf + 4][1]); }
        BAR(); LGKM0();
        __builtin_amdgcn_s_setprio(1);
#pragma unroll
        for (int mf = 0; mf < 4; ++mf)
#pragma unroll
            for (int kk = 0; kk < 2; ++kk) { mfma16(acc[mf + 4][0], af[mf][kk], bf[0][kk]);
                                             mfma16(acc[mf + 4][1], af[mf][kk], bf[1][kk]); }
        __builtin_amdgcn_s_setprio(0);
        BAR();
        // ---- P3: MFMA m4-7 x n2,n3; boundary drain (stage had >=2-phase lead)
        __builtin_amdgcn_s_setprio(1);
#pragma unroll
        for (int mf = 0; mf < 4; ++mf)
#pragma unroll
            for (int kk = 0; kk < 2; ++kk) { mfma16(acc[mf + 4][2], af[mf][kk], bf[2][kk]);
                                             mfma16(acc[mf + 4][3], af[mf][kk], bf[3][kk]); }
        __builtin_amdgcn_s_setprio(0);
        asm volatile("s_waitcnt vmcnt(0)" ::: "memory");
        BAR();
    }

    // epilogue: C/D row=(lane>>4)*4+reg, col=lane&15 [m89]; k-split -> f32 HW atomics
    const int b = n0 >> 12;
    float* ob = out + (long)b * 1048576 + (n0 & 4095) + wn * 64 + (lane & 15);
#pragma unroll
    for (int mf = 0; mf < 8; ++mf)
#pragma unroll
        for (int qi = 0; qi < 4; ++qi) {
            int row = wm * 128 + mf * 16 + (lane >> 4) * 4 + qi;
            float* orow = ob + (long)row * 4096;
#pragma unroll
            for (int nf = 0; nf < 4; ++nf)
                unsafeAtomicAdd(orow + nf * 16, acc[mf][nf][qi]);
        }
}

// ---------------- BatchNorm ----------------

__global__ __launch_bounds__(256) void bn_stats_kernel(const float* __restrict__ out,
                                                       const float* __restrict__ gamma,
                                                       const float* __restrict__ beta,
                                                       float* __restrict__ bnp) {
    int c = blockIdx.x, t = threadIdx.x;
    float s = 0.f, q = 0.f;
    for (int b = 0; b < 8; ++b) {
        const float* p = out + (long)b * 1048576 + (long)c * 4096;
        for (int e = t; e < 4096; e += 256) { float v = p[e]; s += v; q += v * v; }
    }
#pragma unroll
    for (int off = 32; off > 0; off >>= 1) { s += __shfl_down(s, off); q += __shfl_down(q, off); }
    __shared__ float ls[4], lq[4];
    int w = t >> 6;
    if ((t & 63) == 0) { ls[w] = s; lq[w] = q; }
    __syncthreads();
    if (t == 0) {
        s = ls[0] + ls[1] + ls[2] + ls[3];
        q = lq[0] + lq[1] + lq[2] + lq[3];
        float mean = s * (1.f / 32768.f);
        float var = q * (1.f / 32768.f) - mean * mean;
        float sc = gamma[c] * rsqrtf(var + 1e-5f);
        bnp[c] = sc;
        bnp[256 + c] = beta[c] - mean * sc;
    }
}

__global__ __launch_bounds__(256) void bn_apply_kernel(float* __restrict__ out,
                                                       const float* __restrict__ bnp) {
    int i = blockIdx.x * 256 + threadIdx.x;
    f32x4* p = (f32x4*)out;
    f32x4 v = p[i];
    int c = (i >> 10) & 255;
    float sc = bnp[c], sh = bnp[256 + c];
    v = v * sc + sh;
    p[i] = v;
}

// ---------------- launch ----------------

extern "C" void kernel_launch(void* const* d_in, const int* in_sizes, int n_in,
                              void* d_out, int out_size, void* d_ws, size_t ws_size,
                              hipStream_t stream) {
    const float* x     = (const float*)d_in[0];
    const float* wgt   = (const float*)d_in[1];
    const float* gamma = (const float*)d_in[2];
    const float* beta  = (const float*)d_in[3];
    float* out = (float*)d_out;

    unsigned short* xp  = (unsigned short*)d_ws;
    unsigned short* Apk = (unsigned short*)((char*)d_ws + XPACK_BYTES);
    float* bnp          = (float*)((char*)d_ws + XPACK_BYTES + APACK_BYTES);

    zero_ws_kernel<<<8024, 256, 0, stream>>>((ushort8*)xp, XPACK_ELEMS / 8);
    pack_x_kernel<<<4096, 256, 0, stream>>>(x, xp);
    pack_w_kernel<<<256, 256, 0, stream>>>(wgt, Apk);
    zero_out_kernel<<<8192, 256, 0, stream>>>((f32x4*)out);
    gemm_kernel<<<256, 512, 0, stream>>>(Apk, xp, out);
    bn_stats_kernel<<<256, 256, 0, stream>>>(out, gamma, beta, bnp);
    bn_apply_kernel<<<8192, 256, 0, stream>>>(out, bnp);
}